// Round 10
// baseline (224.525 us; speedup 1.0000x reference)
//
#include <hip/hip_runtime.h>

typedef _Float16 half8 __attribute__((ext_vector_type(8)));
typedef _Float16 half4_t __attribute__((ext_vector_type(4)));
typedef float f32x4 __attribute__((ext_vector_type(4)));

#define GK 1024
#define MEG (1024 * 1024)

// async global->LDS, 16B per lane; lptr wave-uniform, lane i's data lands at lptr + i*16
#define GLD16(gptr, lptr) \
    __builtin_amdgcn_global_load_lds((const __attribute__((address_space(1))) void*)(gptr), \
                                     (__attribute__((address_space(3))) void*)(lptr), 16, 0, 0)

// ---------------- fp32 -> fp16 convert (all 5 tensors, one launch) ----------------
__global__ void cvt_all_kernel(const float* __restrict__ hidden,
                               const float* __restrict__ Wq,
                               const float* __restrict__ Wk,
                               const float* __restrict__ Wv,
                               const float* __restrict__ Wo,
                               _Float16* __restrict__ ws) {
    int b = blockIdx.x;
    const float* src;
    _Float16* dst;
    if (b < 4096)      { src = hidden; dst = ws; }
    else if (b < 5120) { src = Wq; dst = ws + 4 * MEG; b -= 4096; }
    else if (b < 6144) { src = Wk; dst = ws + 5 * MEG; b -= 5120; }
    else if (b < 7168) { src = Wv; dst = ws + 6 * MEG; b -= 6144; }
    else               { src = Wo; dst = ws + 7 * MEG; b -= 7168; }
    int i = (b * 256 + threadIdx.x) * 4;
    f32x4 v = *(const f32x4*)(src + i);
    half4_t h;
    h[0] = (_Float16)v[0]; h[1] = (_Float16)v[1];
    h[2] = (_Float16)v[2]; h[3] = (_Float16)v[3];
    *(half4_t*)(dst + i) = h;
}

// ---------------- GEMM: C[4096,1024] = A[4096,1024] @ B[1024,1024]^T ----------------
// R9-proven GLD16 mechanics, BK=64 two-chunk staging.
// MODE 0: z picks (B0,O0)/(B1,O1)/(B2,O2), full K per block.
// MODE 1: split-K=2 — z picks K-half, epilogue atomicAdd into zero-initialized Of.
template<int MODE>
__global__ __launch_bounds__(256) void gemm_kernel(
    const _Float16* __restrict__ A,
    const _Float16* __restrict__ B0,
    const _Float16* __restrict__ B1,
    const _Float16* __restrict__ B2,
    _Float16* __restrict__ O0,
    _Float16* __restrict__ O1,
    _Float16* __restrict__ O2,
    float* __restrict__ Of)
{
    const _Float16* Bw = B0;
    _Float16* Oh = O0;
    if (MODE == 0) {
        int z = blockIdx.z;
        Bw = (z == 0) ? B0 : ((z == 1) ? B1 : B2);
        Oh = (z == 0) ? O0 : ((z == 1) ? O1 : O2);
    }
    const int kbase  = (MODE == 1) ? (int)blockIdx.z * (GK / 2) : 0;
    const int kiters = (MODE == 1) ? (GK / 128) : (GK / 64);

    // two k-chunks of 32 halfs each (R7-proven [128][32] layout per chunk)
    __shared__ __attribute__((aligned(16))) _Float16 sA[2][128][32];
    __shared__ __attribute__((aligned(16))) _Float16 sB[2][128][32];

    const int tid = threadIdx.x;
    const int wave = tid >> 6, lane = tid & 63;
    const int quad = lane >> 4, l16 = lane & 15;
    const int wr = wave >> 1, wc = wave & 1;
    const int M0 = blockIdx.y * 128, N0 = blockIdx.x * 128;

    // staging: per GLD16, lane -> row lane>>2 (16 rows), 16B chunk lane&3 within 32 halfs
    const int rl = lane >> 2;
    const int cl = (lane & 3) * 8;   // halfs within chunk
    const size_t aRow0 = (size_t)(M0 + wave * 16 + rl) * GK + cl + kbase;
    const size_t aRow1 = aRow0 + (size_t)64 * GK;
    const size_t bRow0 = (size_t)(N0 + wave * 16 + rl) * GK + cl + kbase;
    const size_t bRow1 = bRow0 + (size_t)64 * GK;
    _Float16* ldsA[2][2] = {{&sA[0][wave * 16][0], &sA[0][64 + wave * 16][0]},
                            {&sA[1][wave * 16][0], &sA[1][64 + wave * 16][0]}};
    _Float16* ldsB[2][2] = {{&sB[0][wave * 16][0], &sB[0][64 + wave * 16][0]},
                            {&sB[1][wave * 16][0], &sB[1][64 + wave * 16][0]}};

    f32x4 acc[4][4] = {};

    for (int kt = 0; kt < kiters; ++kt) {
        const int ko = kt * 64;
        #pragma unroll
        for (int c = 0; c < 2; ++c) {
            GLD16(A + aRow0 + ko + c * 32, ldsA[c][0]);
            GLD16(A + aRow1 + ko + c * 32, ldsA[c][1]);
            GLD16(Bw + bRow0 + ko + c * 32, ldsB[c][0]);
            GLD16(Bw + bRow1 + ko + c * 32, ldsB[c][1]);
        }
        __syncthreads();                 // drains vmcnt(0): both chunks landed
        #pragma unroll
        for (int c = 0; c < 2; ++c) {
            half8 af[4], bf[4];
            #pragma unroll
            for (int i = 0; i < 4; ++i)
                af[i] = *(const half8*)&sA[c][wr * 64 + i * 16 + l16][quad * 8];
            #pragma unroll
            for (int j = 0; j < 4; ++j)
                bf[j] = *(const half8*)&sB[c][wc * 64 + j * 16 + l16][quad * 8];
            #pragma unroll
            for (int i = 0; i < 4; ++i)
                #pragma unroll
                for (int j = 0; j < 4; ++j)
                    acc[i][j] = __builtin_amdgcn_mfma_f32_16x16x32_f16(af[i], bf[j], acc[i][j], 0, 0, 0);
        }
        __syncthreads();                 // all reads done before next iter's DMA overwrites
    }

    #pragma unroll
    for (int i = 0; i < 4; ++i) {
        #pragma unroll
        for (int j = 0; j < 4; ++j) {
            #pragma unroll
            for (int r = 0; r < 4; ++r) {
                int m = M0 + wr * 64 + i * 16 + quad * 4 + r;
                int n = N0 + wc * 64 + j * 16 + l16;
                float v = acc[i][j][r];
                if (MODE == 0) {
                    int b = m >> 10, s = m & 1023, hh = n >> 6, d = n & 63;
                    Oh[((size_t)((b * 16 + hh) * 1024 + s)) * 64 + d] = (_Float16)v;
                } else {
                    atomicAdd(&Of[(size_t)m * 1024 + n], v);   // split-K accumulate
                }
            }
        }
    }
}

// ---------------- V transpose: [BH][S][64] -> [BH][64][S] (fp16) ----------------
__global__ __launch_bounds__(256) void transpose_v_kernel(
    const _Float16* __restrict__ V, _Float16* __restrict__ VT) {
    __shared__ _Float16 tile[64][65];
    const int s0 = blockIdx.x * 64;
    const int bh = blockIdx.y;
    const _Float16* Vb = V + (size_t)bh * 1024 * 64;
    _Float16* Tb = VT + (size_t)bh * 64 * 1024;
    const int tr = threadIdx.x >> 6;
    const int tc = threadIdx.x & 63;
    #pragma unroll
    for (int i = 0; i < 16; ++i) {
        int r = i * 4 + tr;
        tile[r][tc] = Vb[(size_t)(s0 + r) * 64 + tc];
    }
    __syncthreads();
    #pragma unroll
    for (int i = 0; i < 16; ++i) {
        int d = i * 4 + tr;
        Tb[(size_t)d * 1024 + s0 + tc] = tile[tc][d];
    }
}

// ---------------- flash attention, TRANSPOSED scores (K·Q^T) ----------------
// R9-proven structure. New: sP write->read barrier removed — sP is wave-private and
// same-wave DS ops are program-ordered (compiler inserts lgkmcnt waits for the read).
__global__ __launch_bounds__(256) void attn_kernel(
    const _Float16* __restrict__ Q,
    const _Float16* __restrict__ K,
    const _Float16* __restrict__ VT,
    const float* __restrict__ rel_bias,   // [32][16]
    _Float16* __restrict__ ctx)           // [B*S, 1024]
{
    const int S = 1024;
    const int qt = blockIdx.x;
    const int q0 = qt * 64;
    const int h = blockIdx.y;
    const int b = blockIdx.z;
    const int bh = b * 16 + h;
    const _Float16* Qh = Q + (size_t)bh * S * 64;
    const _Float16* Kh = K + (size_t)bh * S * 64;
    const _Float16* VTh = VT + (size_t)bh * 64 * S;

    __shared__ __attribute__((aligned(16))) _Float16 sQ[64][72];
    __shared__ __attribute__((aligned(16))) _Float16 sK[64][72];
    __shared__ __attribute__((aligned(16))) _Float16 sVt[64][72];   // [d][kpos]
    __shared__ __attribute__((aligned(16))) _Float16 sP[4][16][72]; // [wave][q=l16][kpos]
    __shared__ _Float16 sBias[1088];

    const int tid = threadIdx.x;
    const int wave = tid >> 6, lane = tid & 63;
    const int quad = lane >> 4, l16 = lane & 15;

    {   // stage Q tile (once)
        int r = tid >> 3, c = (tid & 7) * 8;
        *(half8*)&sQ[r][c]      = *(const half8*)(Qh + (size_t)(q0 + r) * 64 + c);
        *(half8*)&sQ[r + 32][c] = *(const half8*)(Qh + (size_t)(q0 + r + 32) * 64 + c);
    }
    // bias window: idx = kpos - q + q0 + 63 in [0,1086]
    for (int i = tid; i < 1087; i += 256) {
        int delta = i - (q0 + 63);             // kpos - q
        int rb = (delta > 0) ? 16 : 0;
        int n = (delta < 0) ? -delta : delta;
        int bucket;
        if (n < 8) bucket = rb + n;
        else bucket = rb + 8 + (n >= 12) + (n >= 16) + (n >= 23) + (n >= 32)
                             + (n >= 46) + (n >= 64) + (n >= 91);
        sBias[i] = (_Float16)rel_bias[bucket * 16 + h];
    }
    __syncthreads();

    // q-fragment: this wave's 16 q-rows (B-operand; lane l16 = q within group)
    half8 qf0 = *(const half8*)&sQ[wave * 16 + l16][quad * 8];
    half8 qf1 = *(const half8*)&sQ[wave * 16 + l16][32 + quad * 8];

    float m_run = -INFINITY, l_run = 0.0f;
    f32x4 acc[4] = {};   // acc[dt][r] = out^T[d = dt*16+quad*4+r][q = l16]

    for (int kt = 0; kt < 16; ++kt) {
        __syncthreads();   // prior iter's sK/sVt reads done
        {
            int r = tid >> 3, c = (tid & 7) * 8;
            *(half8*)&sK[r][c]      = *(const half8*)(Kh + (size_t)(kt * 64 + r) * 64 + c);
            *(half8*)&sK[r + 32][c] = *(const half8*)(Kh + (size_t)(kt * 64 + r + 32) * 64 + c);
            *(half8*)&sVt[r][c]      = *(const half8*)(VTh + (size_t)r * S + kt * 64 + c);
            *(half8*)&sVt[r + 32][c] = *(const half8*)(VTh + (size_t)(r + 32) * S + kt * 64 + c);
        }
        __syncthreads();

        // scores transposed: sc[j][r] = S[kpos = kt*64 + j*16 + quad*4 + r][q = l16]
        f32x4 sc[4] = {};
        #pragma unroll
        for (int j = 0; j < 4; ++j) {
            half8 kf0 = *(const half8*)&sK[j * 16 + l16][quad * 8];
            half8 kf1 = *(const half8*)&sK[j * 16 + l16][32 + quad * 8];
            sc[j] = __builtin_amdgcn_mfma_f32_16x16x32_f16(kf0, qf0, sc[j], 0, 0, 0);
            sc[j] = __builtin_amdgcn_mfma_f32_16x16x32_f16(kf1, qf1, sc[j], 0, 0, 0);
        }

        // bias: idx = kpos - q + q0 + 63; lane's 16 indices are bbase + j*16 + r
        const int bbase = kt * 64 + quad * 4 - wave * 16 - l16 + 63;
        if (kt <= qt - 3 || kt >= qt + 3) {
            // uniform tile: all |delta| >= 129 >= 91 on one side -> one bucket.
            const float cb = (float)sBias[bbase];
            #pragma unroll
            for (int j = 0; j < 4; ++j)
                #pragma unroll
                for (int r = 0; r < 4; ++r)
                    sc[j][r] += cb;
        } else {
            #pragma unroll
            for (int j = 0; j < 4; ++j)
                #pragma unroll
                for (int r = 0; r < 4; ++r)
                    sc[j][r] += (float)sBias[bbase + j * 16 + r];
        }

        // online softmax: each lane owns one q-row's 16 kpos values
        float mx = fmaxf(fmaxf(fmaxf(sc[0][0], sc[0][1]), fmaxf(sc[0][2], sc[0][3])),
                         fmaxf(fmaxf(sc[1][0], sc[1][1]), fmaxf(sc[1][2], sc[1][3])));
        mx = fmaxf(mx, fmaxf(fmaxf(fmaxf(sc[2][0], sc[2][1]), fmaxf(sc[2][2], sc[2][3])),
                             fmaxf(fmaxf(sc[3][0], sc[3][1]), fmaxf(sc[3][2], sc[3][3]))));
        mx = fmaxf(mx, __shfl_xor(mx, 16));
        mx = fmaxf(mx, __shfl_xor(mx, 32));
        float mnew = fmaxf(m_run, mx);
        float alpha = __expf(m_run - mnew);
        m_run = mnew;

        float ps = 0.0f;
        #pragma unroll
        for (int j = 0; j < 4; ++j) {
            half4_t pw;
            #pragma unroll
            for (int r = 0; r < 4; ++r) {
                float p = __expf(sc[j][r] - mnew);
                ps += p;
                pw[r] = (_Float16)p;
            }
            *(half4_t*)&sP[wave][l16][j * 16 + quad * 4] = pw;  // P[q=l16][kpos], b64 write
        }
        l_run = l_run * alpha + ps;
        #pragma unroll
        for (int dt = 0; dt < 4; ++dt) acc[dt] *= alpha;
        // NO barrier: sP slice is wave-private; same-wave ds_write -> ds_read is ordered
        // (compiler emits the lgkmcnt wait for the dependent read).

        half8 pf0 = *(const half8*)&sP[wave][l16][quad * 8];        // B[n=q][k=kpos 0..31]
        half8 pf1 = *(const half8*)&sP[wave][l16][32 + quad * 8];   // kpos 32..63
        #pragma unroll
        for (int dt = 0; dt < 4; ++dt) {
            half8 vf0 = *(const half8*)&sVt[dt * 16 + l16][quad * 8];      // A[m=d][k=kpos]
            half8 vf1 = *(const half8*)&sVt[dt * 16 + l16][32 + quad * 8];
            acc[dt] = __builtin_amdgcn_mfma_f32_16x16x32_f16(vf0, pf0, acc[dt], 0, 0, 0);
            acc[dt] = __builtin_amdgcn_mfma_f32_16x16x32_f16(vf1, pf1, acc[dt], 0, 0, 0);
        }
    }

    // final: reduce row-sum across quads, normalize, store half4 chunks
    l_run += __shfl_xor(l_run, 16);
    l_run += __shfl_xor(l_run, 32);
    const float inv = 1.0f / l_run;
    const size_t qg = (size_t)(b * 1024 + q0 + wave * 16 + l16);
    #pragma unroll
    for (int dt = 0; dt < 4; ++dt) {
        half4_t o;
        #pragma unroll
        for (int r = 0; r < 4; ++r) o[r] = (_Float16)(acc[dt][r] * inv);
        *(half4_t*)&ctx[qg * 1024 + h * 64 + dt * 16 + quad * 4] = o;
    }
}

// ---------------- launch ----------------
extern "C" void kernel_launch(void* const* d_in, const int* in_sizes, int n_in,
                              void* d_out, int out_size, void* d_ws, size_t ws_size,
                              hipStream_t stream) {
    const float* hidden   = (const float*)d_in[0];
    const float* Wq       = (const float*)d_in[1];
    const float* Wk       = (const float*)d_in[2];
    const float* Wv       = (const float*)d_in[3];
    const float* Wo       = (const float*)d_in[4];
    const float* rel_bias = (const float*)d_in[5];
    float* out = (float*)d_out;

    _Float16* ws    = (_Float16*)d_ws;
    _Float16* h16   = ws;                     // 4M halves (reused as VT after gemm<0>)
    _Float16* wq16  = ws + 4 * (size_t)MEG;
    _Float16* wk16  = ws + 5 * (size_t)MEG;
    _Float16* wv16  = ws + 6 * (size_t)MEG;
    _Float16* wo16  = ws + 7 * (size_t)MEG;
    _Float16* Qs    = ws + 8 * (size_t)MEG;   // [B,H,S,64]
    _Float16* Ks    = ws + 12 * (size_t)MEG;
    _Float16* Vs    = ws + 16 * (size_t)MEG;
    _Float16* ctx16 = ws + 20 * (size_t)MEG;  // [B*S,1024]
    _Float16* VTs   = h16;                    // V^T [B,H,64,S] — h16 dead after gemm<0>

    cvt_all_kernel<<<8192, 256, 0, stream>>>(hidden, Wq, Wk, Wv, Wo, ws);

    gemm_kernel<0><<<dim3(8, 32, 3), 256, 0, stream>>>(
        h16, wq16, wk16, wv16, Qs, Ks, Vs, nullptr);

    transpose_v_kernel<<<dim3(16, 64), 256, 0, stream>>>(Vs, VTs);

    attn_kernel<<<dim3(16, 16, 4), 256, 0, stream>>>(Qs, Ks, VTs, rel_bias, ctx16);

    // split-K output GEMM accumulates atomically into zeroed d_out
    hipMemsetAsync(out, 0, (size_t)out_size * sizeof(float), stream);
    gemm_kernel<1><<<dim3(8, 32, 2), 256, 0, stream>>>(
        ctx16, wo16, nullptr, nullptr, nullptr, nullptr, nullptr, out);
}

// Round 11
// 200.416 us; speedup vs baseline: 1.1203x; 1.1203x over previous
//
#include <hip/hip_runtime.h>

typedef _Float16 half8 __attribute__((ext_vector_type(8)));
typedef _Float16 half4_t __attribute__((ext_vector_type(4)));
typedef float f32x4 __attribute__((ext_vector_type(4)));

#define GK 1024
#define MEG (1024 * 1024)

// async global->LDS, 16B per lane; lptr wave-uniform, lane i's data lands at lptr + i*16
#define GLD16(gptr, lptr) \
    __builtin_amdgcn_global_load_lds((const __attribute__((address_space(1))) void*)(gptr), \
                                     (__attribute__((address_space(3))) void*)(lptr), 16, 0, 0)

// ---------------- fp32 -> fp16 convert (all 5 tensors, one launch) ----------------
__global__ void cvt_all_kernel(const float* __restrict__ hidden,
                               const float* __restrict__ Wq,
                               const float* __restrict__ Wk,
                               const float* __restrict__ Wv,
                               const float* __restrict__ Wo,
                               _Float16* __restrict__ ws) {
    int b = blockIdx.x;
    const float* src;
    _Float16* dst;
    if (b < 4096)      { src = hidden; dst = ws; }
    else if (b < 5120) { src = Wq; dst = ws + 4 * MEG; b -= 4096; }
    else if (b < 6144) { src = Wk; dst = ws + 5 * MEG; b -= 5120; }
    else if (b < 7168) { src = Wv; dst = ws + 6 * MEG; b -= 6144; }
    else               { src = Wo; dst = ws + 7 * MEG; b -= 7168; }
    int i = (b * 256 + threadIdx.x) * 4;
    f32x4 v = *(const f32x4*)(src + i);
    half4_t h;
    h[0] = (_Float16)v[0]; h[1] = (_Float16)v[1];
    h[2] = (_Float16)v[2]; h[3] = (_Float16)v[3];
    *(half4_t*)(dst + i) = h;
}

// ---------------- QKV GEMM: C[4096,1024] = A @ B^T, z picks (Wq,Q)/(Wk,K)/(Wv,V) ----------------
// R9-proven GLD16 mechanics, BK=64 two-chunk staging, 128x128 tile, fp16 scatter epilogue.
__global__ __launch_bounds__(256) void gemm_qkv_kernel(
    const _Float16* __restrict__ A,
    const _Float16* __restrict__ B0,
    const _Float16* __restrict__ B1,
    const _Float16* __restrict__ B2,
    _Float16* __restrict__ O0,
    _Float16* __restrict__ O1,
    _Float16* __restrict__ O2)
{
    int z = blockIdx.z;
    const _Float16* Bw = (z == 0) ? B0 : ((z == 1) ? B1 : B2);
    _Float16* Oh = (z == 0) ? O0 : ((z == 1) ? O1 : O2);

    __shared__ __attribute__((aligned(16))) _Float16 sA[2][128][32];
    __shared__ __attribute__((aligned(16))) _Float16 sB[2][128][32];

    const int tid = threadIdx.x;
    const int wave = tid >> 6, lane = tid & 63;
    const int quad = lane >> 4, l16 = lane & 15;
    const int wr = wave >> 1, wc = wave & 1;
    const int M0 = blockIdx.y * 128, N0 = blockIdx.x * 128;

    const int rl = lane >> 2;
    const int cl = (lane & 3) * 8;   // halfs within chunk
    const size_t aRow0 = (size_t)(M0 + wave * 16 + rl) * GK + cl;
    const size_t aRow1 = aRow0 + (size_t)64 * GK;
    const size_t bRow0 = (size_t)(N0 + wave * 16 + rl) * GK + cl;
    const size_t bRow1 = bRow0 + (size_t)64 * GK;
    _Float16* ldsA[2][2] = {{&sA[0][wave * 16][0], &sA[0][64 + wave * 16][0]},
                            {&sA[1][wave * 16][0], &sA[1][64 + wave * 16][0]}};
    _Float16* ldsB[2][2] = {{&sB[0][wave * 16][0], &sB[0][64 + wave * 16][0]},
                            {&sB[1][wave * 16][0], &sB[1][64 + wave * 16][0]}};

    f32x4 acc[4][4] = {};

    for (int kt = 0; kt < GK / 64; ++kt) {
        const int ko = kt * 64;
        #pragma unroll
        for (int c = 0; c < 2; ++c) {
            GLD16(A + aRow0 + ko + c * 32, ldsA[c][0]);
            GLD16(A + aRow1 + ko + c * 32, ldsA[c][1]);
            GLD16(Bw + bRow0 + ko + c * 32, ldsB[c][0]);
            GLD16(Bw + bRow1 + ko + c * 32, ldsB[c][1]);
        }
        __syncthreads();
        #pragma unroll
        for (int c = 0; c < 2; ++c) {
            half8 af[4], bf[4];
            #pragma unroll
            for (int i = 0; i < 4; ++i)
                af[i] = *(const half8*)&sA[c][wr * 64 + i * 16 + l16][quad * 8];
            #pragma unroll
            for (int j = 0; j < 4; ++j)
                bf[j] = *(const half8*)&sB[c][wc * 64 + j * 16 + l16][quad * 8];
            #pragma unroll
            for (int i = 0; i < 4; ++i)
                #pragma unroll
                for (int j = 0; j < 4; ++j)
                    acc[i][j] = __builtin_amdgcn_mfma_f32_16x16x32_f16(af[i], bf[j], acc[i][j], 0, 0, 0);
        }
        __syncthreads();
    }

    #pragma unroll
    for (int i = 0; i < 4; ++i) {
        #pragma unroll
        for (int j = 0; j < 4; ++j) {
            #pragma unroll
            for (int r = 0; r < 4; ++r) {
                int m = M0 + wr * 64 + i * 16 + quad * 4 + r;
                int n = N0 + wc * 64 + j * 16 + l16;
                int b = m >> 10, s = m & 1023, hh = n >> 6, d = n & 63;
                Oh[((size_t)((b * 16 + hh) * 1024 + s)) * 64 + d] = (_Float16)acc[i][j][r];
            }
        }
    }
}

// ---------------- Output GEMM: C[4096,1024] fp32 = A @ B^T ----------------
// Split-M: 64x128 tile, grid (8,64) = 512 blocks = 2 blocks/CU, plain stores, full K.
__global__ __launch_bounds__(256) void gemm_o_kernel(
    const _Float16* __restrict__ A,
    const _Float16* __restrict__ Bw,
    float* __restrict__ Of)
{
    __shared__ __attribute__((aligned(16))) _Float16 sA[2][64][32];
    __shared__ __attribute__((aligned(16))) _Float16 sB[2][128][32];

    const int tid = threadIdx.x;
    const int wave = tid >> 6, lane = tid & 63;
    const int quad = lane >> 4, l16 = lane & 15;
    const int M0 = blockIdx.y * 64, N0 = blockIdx.x * 128;

    const int rl = lane >> 2;
    const int cl = (lane & 3) * 8;
    const size_t aRow  = (size_t)(M0 + wave * 16 + rl) * GK + cl;
    const size_t bRow0 = (size_t)(N0 + wave * 16 + rl) * GK + cl;
    const size_t bRow1 = bRow0 + (size_t)64 * GK;
    _Float16* ldsA[2]    = {&sA[0][wave * 16][0], &sA[1][wave * 16][0]};
    _Float16* ldsB[2][2] = {{&sB[0][wave * 16][0], &sB[0][64 + wave * 16][0]},
                            {&sB[1][wave * 16][0], &sB[1][64 + wave * 16][0]}};

    f32x4 acc[4][2] = {};

    for (int kt = 0; kt < GK / 64; ++kt) {
        const int ko = kt * 64;
        #pragma unroll
        for (int c = 0; c < 2; ++c) {
            GLD16(A + aRow + ko + c * 32, ldsA[c]);
            GLD16(Bw + bRow0 + ko + c * 32, ldsB[c][0]);
            GLD16(Bw + bRow1 + ko + c * 32, ldsB[c][1]);
        }
        __syncthreads();
        #pragma unroll
        for (int c = 0; c < 2; ++c) {
            half8 af[4], bf[2];
            #pragma unroll
            for (int i = 0; i < 4; ++i)
                af[i] = *(const half8*)&sA[c][i * 16 + l16][quad * 8];
            #pragma unroll
            for (int j = 0; j < 2; ++j)
                bf[j] = *(const half8*)&sB[c][wave * 32 + j * 16 + l16][quad * 8];
            #pragma unroll
            for (int i = 0; i < 4; ++i)
                #pragma unroll
                for (int j = 0; j < 2; ++j)
                    acc[i][j] = __builtin_amdgcn_mfma_f32_16x16x32_f16(af[i], bf[j], acc[i][j], 0, 0, 0);
        }
        __syncthreads();
    }

    #pragma unroll
    for (int i = 0; i < 4; ++i) {
        #pragma unroll
        for (int j = 0; j < 2; ++j) {
            #pragma unroll
            for (int r = 0; r < 4; ++r) {
                int m = M0 + i * 16 + quad * 4 + r;
                int n = N0 + wave * 32 + j * 16 + l16;
                Of[(size_t)m * 1024 + n] = acc[i][j][r];
            }
        }
    }
}

// ---------------- V transpose: [BH][S][64] -> [BH][64][S] (fp16) ----------------
__global__ __launch_bounds__(256) void transpose_v_kernel(
    const _Float16* __restrict__ V, _Float16* __restrict__ VT) {
    __shared__ _Float16 tile[64][65];
    const int s0 = blockIdx.x * 64;
    const int bh = blockIdx.y;
    const _Float16* Vb = V + (size_t)bh * 1024 * 64;
    _Float16* Tb = VT + (size_t)bh * 64 * 1024;
    const int tr = threadIdx.x >> 6;
    const int tc = threadIdx.x & 63;
    #pragma unroll
    for (int i = 0; i < 16; ++i) {
        int r = i * 4 + tr;
        tile[r][tc] = Vb[(size_t)(s0 + r) * 64 + tc];
    }
    __syncthreads();
    #pragma unroll
    for (int i = 0; i < 16; ++i) {
        int d = i * 4 + tr;
        Tb[(size_t)d * 1024 + s0 + tc] = tile[tc][d];
    }
}

// ---------------- flash attention, TRANSPOSED scores (K·Q^T) ----------------
// R10-proven structure (no sP barrier). New: global staging pointers hoisted out of
// the kt loop (increment by constant stride) — attn is VALU-issue-bound.
__global__ __launch_bounds__(256) void attn_kernel(
    const _Float16* __restrict__ Q,
    const _Float16* __restrict__ K,
    const _Float16* __restrict__ VT,
    const float* __restrict__ rel_bias,   // [32][16]
    _Float16* __restrict__ ctx)           // [B*S, 1024]
{
    const int S = 1024;
    const int qt = blockIdx.x;
    const int q0 = qt * 64;
    const int h = blockIdx.y;
    const int b = blockIdx.z;
    const int bh = b * 16 + h;
    const _Float16* Qh = Q + (size_t)bh * S * 64;
    const _Float16* Kh = K + (size_t)bh * S * 64;
    const _Float16* VTh = VT + (size_t)bh * 64 * S;

    __shared__ __attribute__((aligned(16))) _Float16 sQ[64][72];
    __shared__ __attribute__((aligned(16))) _Float16 sK[64][72];
    __shared__ __attribute__((aligned(16))) _Float16 sVt[64][72];   // [d][kpos]
    __shared__ __attribute__((aligned(16))) _Float16 sP[4][16][72]; // [wave][q=l16][kpos]
    __shared__ _Float16 sBias[1088];

    const int tid = threadIdx.x;
    const int wave = tid >> 6, lane = tid & 63;
    const int quad = lane >> 4, l16 = lane & 15;

    {   // stage Q tile (once)
        int r = tid >> 3, c = (tid & 7) * 8;
        *(half8*)&sQ[r][c]      = *(const half8*)(Qh + (size_t)(q0 + r) * 64 + c);
        *(half8*)&sQ[r + 32][c] = *(const half8*)(Qh + (size_t)(q0 + r + 32) * 64 + c);
    }
    // bias window: idx = kpos - q + q0 + 63 in [0,1086]
    for (int i = tid; i < 1087; i += 256) {
        int delta = i - (q0 + 63);             // kpos - q
        int rb = (delta > 0) ? 16 : 0;
        int n = (delta < 0) ? -delta : delta;
        int bucket;
        if (n < 8) bucket = rb + n;
        else bucket = rb + 8 + (n >= 12) + (n >= 16) + (n >= 23) + (n >= 32)
                             + (n >= 46) + (n >= 64) + (n >= 91);
        sBias[i] = (_Float16)rel_bias[bucket * 16 + h];
    }
    __syncthreads();

    // q-fragment: this wave's 16 q-rows (B-operand; lane l16 = q within group)
    half8 qf0 = *(const half8*)&sQ[wave * 16 + l16][quad * 8];
    half8 qf1 = *(const half8*)&sQ[wave * 16 + l16][32 + quad * 8];

    // hoisted staging pointers (advance by constant stride per kt)
    const int sr = tid >> 3;            // 0..31
    const int sc_ = (tid & 7) * 8;      // 0..56
    const _Float16* kp0 = Kh + (size_t)sr * 64 + sc_;          // += 4096 per kt
    const _Float16* kp1 = kp0 + (size_t)32 * 64;
    const _Float16* vp0 = VTh + (size_t)sr * S + sc_;          // += 64 per kt
    const _Float16* vp1 = vp0 + (size_t)32 * S;
    _Float16* sKw0 = &sK[sr][sc_];
    _Float16* sKw1 = &sK[sr + 32][sc_];
    _Float16* sVw0 = &sVt[sr][sc_];
    _Float16* sVw1 = &sVt[sr + 32][sc_];

    float m_run = -INFINITY, l_run = 0.0f;
    f32x4 acc[4] = {};   // acc[dt][r] = out^T[d = dt*16+quad*4+r][q = l16]

    for (int kt = 0; kt < 16; ++kt) {
        __syncthreads();   // prior iter's sK/sVt reads done
        *(half8*)sKw0 = *(const half8*)kp0;
        *(half8*)sKw1 = *(const half8*)kp1;
        *(half8*)sVw0 = *(const half8*)vp0;
        *(half8*)sVw1 = *(const half8*)vp1;
        kp0 += 4096; kp1 += 4096; vp0 += 64; vp1 += 64;
        __syncthreads();

        // scores transposed: sc[j][r] = S[kpos = kt*64 + j*16 + quad*4 + r][q = l16]
        f32x4 sc[4] = {};
        #pragma unroll
        for (int j = 0; j < 4; ++j) {
            half8 kf0 = *(const half8*)&sK[j * 16 + l16][quad * 8];
            half8 kf1 = *(const half8*)&sK[j * 16 + l16][32 + quad * 8];
            sc[j] = __builtin_amdgcn_mfma_f32_16x16x32_f16(kf0, qf0, sc[j], 0, 0, 0);
            sc[j] = __builtin_amdgcn_mfma_f32_16x16x32_f16(kf1, qf1, sc[j], 0, 0, 0);
        }

        // bias: idx = kpos - q + q0 + 63; lane's 16 indices are bbase + j*16 + r
        const int bbase = kt * 64 + quad * 4 - wave * 16 - l16 + 63;
        if (kt <= qt - 3 || kt >= qt + 3) {
            // uniform tile: all |delta| >= 129 >= 91 on one side -> one bucket.
            const float cb = (float)sBias[bbase];
            #pragma unroll
            for (int j = 0; j < 4; ++j)
                #pragma unroll
                for (int r = 0; r < 4; ++r)
                    sc[j][r] += cb;
        } else {
            #pragma unroll
            for (int j = 0; j < 4; ++j)
                #pragma unroll
                for (int r = 0; r < 4; ++r)
                    sc[j][r] += (float)sBias[bbase + j * 16 + r];
        }

        // online softmax: each lane owns one q-row's 16 kpos values
        float mx = fmaxf(fmaxf(fmaxf(sc[0][0], sc[0][1]), fmaxf(sc[0][2], sc[0][3])),
                         fmaxf(fmaxf(sc[1][0], sc[1][1]), fmaxf(sc[1][2], sc[1][3])));
        mx = fmaxf(mx, fmaxf(fmaxf(fmaxf(sc[2][0], sc[2][1]), fmaxf(sc[2][2], sc[2][3])),
                             fmaxf(fmaxf(sc[3][0], sc[3][1]), fmaxf(sc[3][2], sc[3][3]))));
        mx = fmaxf(mx, __shfl_xor(mx, 16));
        mx = fmaxf(mx, __shfl_xor(mx, 32));
        float mnew = fmaxf(m_run, mx);
        float alpha = __expf(m_run - mnew);
        m_run = mnew;

        float ps = 0.0f;
        #pragma unroll
        for (int j = 0; j < 4; ++j) {
            half4_t pw;
            #pragma unroll
            for (int r = 0; r < 4; ++r) {
                float p = __expf(sc[j][r] - mnew);
                ps += p;
                pw[r] = (_Float16)p;
            }
            *(half4_t*)&sP[wave][l16][j * 16 + quad * 4] = pw;  // P[q=l16][kpos], b64 write
        }
        l_run = l_run * alpha + ps;
        #pragma unroll
        for (int dt = 0; dt < 4; ++dt) acc[dt] *= alpha;
        // NO barrier: sP slice is wave-private; same-wave ds_write -> ds_read is ordered.

        half8 pf0 = *(const half8*)&sP[wave][l16][quad * 8];        // B[n=q][k=kpos 0..31]
        half8 pf1 = *(const half8*)&sP[wave][l16][32 + quad * 8];   // kpos 32..63
        #pragma unroll
        for (int dt = 0; dt < 4; ++dt) {
            half8 vf0 = *(const half8*)&sVt[dt * 16 + l16][quad * 8];      // A[m=d][k=kpos]
            half8 vf1 = *(const half8*)&sVt[dt * 16 + l16][32 + quad * 8];
            acc[dt] = __builtin_amdgcn_mfma_f32_16x16x32_f16(vf0, pf0, acc[dt], 0, 0, 0);
            acc[dt] = __builtin_amdgcn_mfma_f32_16x16x32_f16(vf1, pf1, acc[dt], 0, 0, 0);
        }
    }

    // final: reduce row-sum across quads, normalize, store half4 chunks
    l_run += __shfl_xor(l_run, 16);
    l_run += __shfl_xor(l_run, 32);
    const float inv = 1.0f / l_run;
    const size_t qg = (size_t)(b * 1024 + q0 + wave * 16 + l16);
    #pragma unroll
    for (int dt = 0; dt < 4; ++dt) {
        half4_t o;
        #pragma unroll
        for (int r = 0; r < 4; ++r) o[r] = (_Float16)(acc[dt][r] * inv);
        *(half4_t*)&ctx[qg * 1024 + h * 64 + dt * 16 + quad * 4] = o;
    }
}

// ---------------- launch ----------------
extern "C" void kernel_launch(void* const* d_in, const int* in_sizes, int n_in,
                              void* d_out, int out_size, void* d_ws, size_t ws_size,
                              hipStream_t stream) {
    const float* hidden   = (const float*)d_in[0];
    const float* Wq       = (const float*)d_in[1];
    const float* Wk       = (const float*)d_in[2];
    const float* Wv       = (const float*)d_in[3];
    const float* Wo       = (const float*)d_in[4];
    const float* rel_bias = (const float*)d_in[5];
    float* out = (float*)d_out;

    _Float16* ws    = (_Float16*)d_ws;
    _Float16* h16   = ws;                     // 4M halves (reused as VT after gemm_qkv)
    _Float16* wq16  = ws + 4 * (size_t)MEG;
    _Float16* wk16  = ws + 5 * (size_t)MEG;
    _Float16* wv16  = ws + 6 * (size_t)MEG;
    _Float16* wo16  = ws + 7 * (size_t)MEG;
    _Float16* Qs    = ws + 8 * (size_t)MEG;   // [B,H,S,64]
    _Float16* Ks    = ws + 12 * (size_t)MEG;
    _Float16* Vs    = ws + 16 * (size_t)MEG;
    _Float16* ctx16 = ws + 20 * (size_t)MEG;  // [B*S,1024]
    _Float16* VTs   = h16;                    // V^T [B,H,64,S] — h16 dead after gemm_qkv

    cvt_all_kernel<<<8192, 256, 0, stream>>>(hidden, Wq, Wk, Wv, Wo, ws);

    gemm_qkv_kernel<<<dim3(8, 32, 3), 256, 0, stream>>>(
        h16, wq16, wk16, wv16, Qs, Ks, Vs);

    transpose_v_kernel<<<dim3(16, 64), 256, 0, stream>>>(Vs, VTs);

    attn_kernel<<<dim3(16, 16, 4), 256, 0, stream>>>(Qs, Ks, VTs, rel_bias, ctx16);

    gemm_o_kernel<<<dim3(8, 64), 256, 0, stream>>>(ctx16, wo16, out);
}

// Round 12
// 198.333 us; speedup vs baseline: 1.1321x; 1.0105x over previous
//
#include <hip/hip_runtime.h>

typedef _Float16 half8 __attribute__((ext_vector_type(8)));
typedef _Float16 half4_t __attribute__((ext_vector_type(4)));
typedef float f32x4 __attribute__((ext_vector_type(4)));

#define GK 1024
#define MEG (1024 * 1024)
#define LOG2E 1.44269504088896f

// async global->LDS, 16B per lane; lptr wave-uniform, lane i's data lands at lptr + i*16
#define GLD16(gptr, lptr) \
    __builtin_amdgcn_global_load_lds((const __attribute__((address_space(1))) void*)(gptr), \
                                     (__attribute__((address_space(3))) void*)(lptr), 16, 0, 0)

// ---------------- fp32 -> fp16 convert (all 5 tensors, one launch) ----------------
__global__ void cvt_all_kernel(const float* __restrict__ hidden,
                               const float* __restrict__ Wq,
                               const float* __restrict__ Wk,
                               const float* __restrict__ Wv,
                               const float* __restrict__ Wo,
                               _Float16* __restrict__ ws) {
    int b = blockIdx.x;
    const float* src;
    _Float16* dst;
    if (b < 4096)      { src = hidden; dst = ws; }
    else if (b < 5120) { src = Wq; dst = ws + 4 * MEG; b -= 4096; }
    else if (b < 6144) { src = Wk; dst = ws + 5 * MEG; b -= 5120; }
    else if (b < 7168) { src = Wv; dst = ws + 6 * MEG; b -= 6144; }
    else               { src = Wo; dst = ws + 7 * MEG; b -= 7168; }
    int i = (b * 256 + threadIdx.x) * 4;
    f32x4 v = *(const f32x4*)(src + i);
    half4_t h;
    h[0] = (_Float16)v[0]; h[1] = (_Float16)v[1];
    h[2] = (_Float16)v[2]; h[3] = (_Float16)v[3];
    *(half4_t*)(dst + i) = h;
}

// ---------------- QKV GEMM: C[4096,1024] = A @ B^T, z picks (Wq,Q)/(Wk,K)/(Wv,V) ----------------
__global__ __launch_bounds__(256) void gemm_qkv_kernel(
    const _Float16* __restrict__ A,
    const _Float16* __restrict__ B0,
    const _Float16* __restrict__ B1,
    const _Float16* __restrict__ B2,
    _Float16* __restrict__ O0,
    _Float16* __restrict__ O1,
    _Float16* __restrict__ O2)
{
    int z = blockIdx.z;
    const _Float16* Bw = (z == 0) ? B0 : ((z == 1) ? B1 : B2);
    _Float16* Oh = (z == 0) ? O0 : ((z == 1) ? O1 : O2);

    __shared__ __attribute__((aligned(16))) _Float16 sA[2][128][32];
    __shared__ __attribute__((aligned(16))) _Float16 sB[2][128][32];

    const int tid = threadIdx.x;
    const int wave = tid >> 6, lane = tid & 63;
    const int quad = lane >> 4, l16 = lane & 15;
    const int wr = wave >> 1, wc = wave & 1;
    const int M0 = blockIdx.y * 128, N0 = blockIdx.x * 128;

    const int rl = lane >> 2;
    const int cl = (lane & 3) * 8;   // halfs within chunk
    const size_t aRow0 = (size_t)(M0 + wave * 16 + rl) * GK + cl;
    const size_t aRow1 = aRow0 + (size_t)64 * GK;
    const size_t bRow0 = (size_t)(N0 + wave * 16 + rl) * GK + cl;
    const size_t bRow1 = bRow0 + (size_t)64 * GK;
    _Float16* ldsA[2][2] = {{&sA[0][wave * 16][0], &sA[0][64 + wave * 16][0]},
                            {&sA[1][wave * 16][0], &sA[1][64 + wave * 16][0]}};
    _Float16* ldsB[2][2] = {{&sB[0][wave * 16][0], &sB[0][64 + wave * 16][0]},
                            {&sB[1][wave * 16][0], &sB[1][64 + wave * 16][0]}};

    f32x4 acc[4][4] = {};

    for (int kt = 0; kt < GK / 64; ++kt) {
        const int ko = kt * 64;
        #pragma unroll
        for (int c = 0; c < 2; ++c) {
            GLD16(A + aRow0 + ko + c * 32, ldsA[c][0]);
            GLD16(A + aRow1 + ko + c * 32, ldsA[c][1]);
            GLD16(Bw + bRow0 + ko + c * 32, ldsB[c][0]);
            GLD16(Bw + bRow1 + ko + c * 32, ldsB[c][1]);
        }
        __syncthreads();
        #pragma unroll
        for (int c = 0; c < 2; ++c) {
            half8 af[4], bf[4];
            #pragma unroll
            for (int i = 0; i < 4; ++i)
                af[i] = *(const half8*)&sA[c][wr * 64 + i * 16 + l16][quad * 8];
            #pragma unroll
            for (int j = 0; j < 4; ++j)
                bf[j] = *(const half8*)&sB[c][wc * 64 + j * 16 + l16][quad * 8];
            #pragma unroll
            for (int i = 0; i < 4; ++i)
                #pragma unroll
                for (int j = 0; j < 4; ++j)
                    acc[i][j] = __builtin_amdgcn_mfma_f32_16x16x32_f16(af[i], bf[j], acc[i][j], 0, 0, 0);
        }
        __syncthreads();
    }

    #pragma unroll
    for (int i = 0; i < 4; ++i) {
        #pragma unroll
        for (int j = 0; j < 4; ++j) {
            #pragma unroll
            for (int r = 0; r < 4; ++r) {
                int m = M0 + wr * 64 + i * 16 + quad * 4 + r;
                int n = N0 + wc * 64 + j * 16 + l16;
                int b = m >> 10, s = m & 1023, hh = n >> 6, d = n & 63;
                Oh[((size_t)((b * 16 + hh) * 1024 + s)) * 64 + d] = (_Float16)acc[i][j][r];
            }
        }
    }
}

// ---------------- Output GEMM: C[4096,1024] fp32 = A @ B^T ----------------
// Split-M: 64x128 tile, grid (8,64) = 512 blocks = 2 blocks/CU, plain stores, full K.
__global__ __launch_bounds__(256) void gemm_o_kernel(
    const _Float16* __restrict__ A,
    const _Float16* __restrict__ Bw,
    float* __restrict__ Of)
{
    __shared__ __attribute__((aligned(16))) _Float16 sA[2][64][32];
    __shared__ __attribute__((aligned(16))) _Float16 sB[2][128][32];

    const int tid = threadIdx.x;
    const int wave = tid >> 6, lane = tid & 63;
    const int quad = lane >> 4, l16 = lane & 15;
    const int M0 = blockIdx.y * 64, N0 = blockIdx.x * 128;

    const int rl = lane >> 2;
    const int cl = (lane & 3) * 8;
    const size_t aRow  = (size_t)(M0 + wave * 16 + rl) * GK + cl;
    const size_t bRow0 = (size_t)(N0 + wave * 16 + rl) * GK + cl;
    const size_t bRow1 = bRow0 + (size_t)64 * GK;
    _Float16* ldsA[2]    = {&sA[0][wave * 16][0], &sA[1][wave * 16][0]};
    _Float16* ldsB[2][2] = {{&sB[0][wave * 16][0], &sB[0][64 + wave * 16][0]},
                            {&sB[1][wave * 16][0], &sB[1][64 + wave * 16][0]}};

    f32x4 acc[4][2] = {};

    for (int kt = 0; kt < GK / 64; ++kt) {
        const int ko = kt * 64;
        #pragma unroll
        for (int c = 0; c < 2; ++c) {
            GLD16(A + aRow + ko + c * 32, ldsA[c]);
            GLD16(Bw + bRow0 + ko + c * 32, ldsB[c][0]);
            GLD16(Bw + bRow1 + ko + c * 32, ldsB[c][1]);
        }
        __syncthreads();
        #pragma unroll
        for (int c = 0; c < 2; ++c) {
            half8 af[4], bf[2];
            #pragma unroll
            for (int i = 0; i < 4; ++i)
                af[i] = *(const half8*)&sA[c][i * 16 + l16][quad * 8];
            #pragma unroll
            for (int j = 0; j < 2; ++j)
                bf[j] = *(const half8*)&sB[c][wave * 32 + j * 16 + l16][quad * 8];
            #pragma unroll
            for (int i = 0; i < 4; ++i)
                #pragma unroll
                for (int j = 0; j < 2; ++j)
                    acc[i][j] = __builtin_amdgcn_mfma_f32_16x16x32_f16(af[i], bf[j], acc[i][j], 0, 0, 0);
        }
        __syncthreads();
    }

    #pragma unroll
    for (int i = 0; i < 4; ++i) {
        #pragma unroll
        for (int j = 0; j < 2; ++j) {
            #pragma unroll
            for (int r = 0; r < 4; ++r) {
                int m = M0 + i * 16 + quad * 4 + r;
                int n = N0 + wave * 32 + j * 16 + l16;
                Of[(size_t)m * 1024 + n] = acc[i][j][r];
            }
        }
    }
}

// ---------------- V transpose: [BH][S][64] -> [BH][64][S] (fp16) ----------------
__global__ __launch_bounds__(256) void transpose_v_kernel(
    const _Float16* __restrict__ V, _Float16* __restrict__ VT) {
    __shared__ _Float16 tile[64][65];
    const int s0 = blockIdx.x * 64;
    const int bh = blockIdx.y;
    const _Float16* Vb = V + (size_t)bh * 1024 * 64;
    _Float16* Tb = VT + (size_t)bh * 64 * 1024;
    const int tr = threadIdx.x >> 6;
    const int tc = threadIdx.x & 63;
    #pragma unroll
    for (int i = 0; i < 16; ++i) {
        int r = i * 4 + tr;
        tile[r][tc] = Vb[(size_t)(s0 + r) * 64 + tc];
    }
    __syncthreads();
    #pragma unroll
    for (int i = 0; i < 16; ++i) {
        int d = i * 4 + tr;
        Tb[(size_t)d * 1024 + s0 + tc] = tile[tc][d];
    }
}

// ---------------- flash attention, TRANSPOSED scores (K·Q^T) ----------------
// R11-proven structure. New: (1) register-prefetch staging — next tile loaded into
// VGPRs during compute, LDS-written next iter (global latency hidden); (2) exp2-domain
// softmax on uniform-bias tiles: p = exp2(fma(sc, log2e, (cb-mnew)*log2e)).
__global__ __launch_bounds__(256) void attn_kernel(
    const _Float16* __restrict__ Q,
    const _Float16* __restrict__ K,
    const _Float16* __restrict__ VT,
    const float* __restrict__ rel_bias,   // [32][16]
    _Float16* __restrict__ ctx)           // [B*S, 1024]
{
    const int S = 1024;
    const int qt = blockIdx.x;
    const int q0 = qt * 64;
    const int h = blockIdx.y;
    const int b = blockIdx.z;
    const int bh = b * 16 + h;
    const _Float16* Qh = Q + (size_t)bh * S * 64;
    const _Float16* Kh = K + (size_t)bh * S * 64;
    const _Float16* VTh = VT + (size_t)bh * 64 * S;

    __shared__ __attribute__((aligned(16))) _Float16 sQ[64][72];
    __shared__ __attribute__((aligned(16))) _Float16 sK[64][72];
    __shared__ __attribute__((aligned(16))) _Float16 sVt[64][72];   // [d][kpos]
    __shared__ __attribute__((aligned(16))) _Float16 sP[4][16][72]; // [wave][q=l16][kpos]
    __shared__ _Float16 sBias[1088];

    const int tid = threadIdx.x;
    const int wave = tid >> 6, lane = tid & 63;
    const int quad = lane >> 4, l16 = lane & 15;

    {   // stage Q tile (once)
        int r = tid >> 3, c = (tid & 7) * 8;
        *(half8*)&sQ[r][c]      = *(const half8*)(Qh + (size_t)(q0 + r) * 64 + c);
        *(half8*)&sQ[r + 32][c] = *(const half8*)(Qh + (size_t)(q0 + r + 32) * 64 + c);
    }
    // bias window: idx = kpos - q + q0 + 63 in [0,1086]
    for (int i = tid; i < 1087; i += 256) {
        int delta = i - (q0 + 63);             // kpos - q
        int rb = (delta > 0) ? 16 : 0;
        int n = (delta < 0) ? -delta : delta;
        int bucket;
        if (n < 8) bucket = rb + n;
        else bucket = rb + 8 + (n >= 12) + (n >= 16) + (n >= 23) + (n >= 32)
                             + (n >= 46) + (n >= 64) + (n >= 91);
        sBias[i] = (_Float16)rel_bias[bucket * 16 + h];
    }
    __syncthreads();

    // q-fragment: this wave's 16 q-rows (B-operand; lane l16 = q within group)
    half8 qf0 = *(const half8*)&sQ[wave * 16 + l16][quad * 8];
    half8 qf1 = *(const half8*)&sQ[wave * 16 + l16][32 + quad * 8];

    // staging pointers (advance by constant stride per kt)
    const int sr = tid >> 3;            // 0..31
    const int sc_ = (tid & 7) * 8;      // 0..56
    const _Float16* kp0 = Kh + (size_t)sr * 64 + sc_;          // += 4096 per kt
    const _Float16* kp1 = kp0 + (size_t)32 * 64;
    const _Float16* vp0 = VTh + (size_t)sr * S + sc_;          // += 64 per kt
    const _Float16* vp1 = vp0 + (size_t)32 * S;
    _Float16* sKw0 = &sK[sr][sc_];
    _Float16* sKw1 = &sK[sr + 32][sc_];
    _Float16* sVw0 = &sVt[sr][sc_];
    _Float16* sVw1 = &sVt[sr + 32][sc_];

    // preload tile kt=0 into registers
    half8 rk0 = *(const half8*)kp0;
    half8 rk1 = *(const half8*)kp1;
    half8 rv0 = *(const half8*)vp0;
    half8 rv1 = *(const half8*)vp1;
    kp0 += 4096; kp1 += 4096; vp0 += 64; vp1 += 64;

    float m_run = -INFINITY, l_run = 0.0f;
    f32x4 acc[4] = {};   // acc[dt][r] = out^T[d = dt*16+quad*4+r][q = l16]

    for (int kt = 0; kt < 16; ++kt) {
        __syncthreads();   // prior iter's sK/sVt reads done
        *(half8*)sKw0 = rk0;
        *(half8*)sKw1 = rk1;
        *(half8*)sVw0 = rv0;
        *(half8*)sVw1 = rv1;
        __syncthreads();   // tile visible to all waves
        if (kt < 15) {     // prefetch next tile; latency hidden by compute below
            rk0 = *(const half8*)kp0;
            rk1 = *(const half8*)kp1;
            rv0 = *(const half8*)vp0;
            rv1 = *(const half8*)vp1;
            kp0 += 4096; kp1 += 4096; vp0 += 64; vp1 += 64;
        }

        // scores transposed: sc[j][r] = S[kpos = kt*64 + j*16 + quad*4 + r][q = l16]
        f32x4 sc[4] = {};
        #pragma unroll
        for (int j = 0; j < 4; ++j) {
            half8 kf0 = *(const half8*)&sK[j * 16 + l16][quad * 8];
            half8 kf1 = *(const half8*)&sK[j * 16 + l16][32 + quad * 8];
            sc[j] = __builtin_amdgcn_mfma_f32_16x16x32_f16(kf0, qf0, sc[j], 0, 0, 0);
            sc[j] = __builtin_amdgcn_mfma_f32_16x16x32_f16(kf1, qf1, sc[j], 0, 0, 0);
        }

        const int bbase = kt * 64 + quad * 4 - wave * 16 - l16 + 63;
        float ps = 0.0f;
        if (kt <= qt - 3 || kt >= qt + 3) {
            // uniform tile: one bucket -> bias is lane-uniform; fold bias & max into exp2 arg
            const float cb = (float)sBias[bbase];
            float mx = fmaxf(fmaxf(fmaxf(sc[0][0], sc[0][1]), fmaxf(sc[0][2], sc[0][3])),
                             fmaxf(fmaxf(sc[1][0], sc[1][1]), fmaxf(sc[1][2], sc[1][3])));
            mx = fmaxf(mx, fmaxf(fmaxf(fmaxf(sc[2][0], sc[2][1]), fmaxf(sc[2][2], sc[2][3])),
                                 fmaxf(fmaxf(sc[3][0], sc[3][1]), fmaxf(sc[3][2], sc[3][3]))));
            mx = fmaxf(mx, __shfl_xor(mx, 16));
            mx = fmaxf(mx, __shfl_xor(mx, 32));
            float mnew = fmaxf(m_run, mx + cb);
            float alpha = __expf(m_run - mnew);
            m_run = mnew;
            const float kk = (cb - mnew) * LOG2E;
            #pragma unroll
            for (int j = 0; j < 4; ++j) {
                half4_t pw;
                #pragma unroll
                for (int r = 0; r < 4; ++r) {
                    float p = __builtin_exp2f(__builtin_fmaf(sc[j][r], LOG2E, kk));
                    ps += p;
                    pw[r] = (_Float16)p;
                }
                *(half4_t*)&sP[wave][l16][j * 16 + quad * 4] = pw;
            }
            l_run = l_run * alpha + ps;
            #pragma unroll
            for (int dt = 0; dt < 4; ++dt) acc[dt] *= alpha;
        } else {
            // mixed tile: per-element bias (R11-exact path)
            #pragma unroll
            for (int j = 0; j < 4; ++j)
                #pragma unroll
                for (int r = 0; r < 4; ++r)
                    sc[j][r] += (float)sBias[bbase + j * 16 + r];
            float mx = fmaxf(fmaxf(fmaxf(sc[0][0], sc[0][1]), fmaxf(sc[0][2], sc[0][3])),
                             fmaxf(fmaxf(sc[1][0], sc[1][1]), fmaxf(sc[1][2], sc[1][3])));
            mx = fmaxf(mx, fmaxf(fmaxf(fmaxf(sc[2][0], sc[2][1]), fmaxf(sc[2][2], sc[2][3])),
                                 fmaxf(fmaxf(sc[3][0], sc[3][1]), fmaxf(sc[3][2], sc[3][3]))));
            mx = fmaxf(mx, __shfl_xor(mx, 16));
            mx = fmaxf(mx, __shfl_xor(mx, 32));
            float mnew = fmaxf(m_run, mx);
            float alpha = __expf(m_run - mnew);
            m_run = mnew;
            #pragma unroll
            for (int j = 0; j < 4; ++j) {
                half4_t pw;
                #pragma unroll
                for (int r = 0; r < 4; ++r) {
                    float p = __expf(sc[j][r] - mnew);
                    ps += p;
                    pw[r] = (_Float16)p;
                }
                *(half4_t*)&sP[wave][l16][j * 16 + quad * 4] = pw;
            }
            l_run = l_run * alpha + ps;
            #pragma unroll
            for (int dt = 0; dt < 4; ++dt) acc[dt] *= alpha;
        }
        // NO barrier: sP slice is wave-private; same-wave ds_write -> ds_read is ordered.

        half8 pf0 = *(const half8*)&sP[wave][l16][quad * 8];        // B[n=q][k=kpos 0..31]
        half8 pf1 = *(const half8*)&sP[wave][l16][32 + quad * 8];   // kpos 32..63
        #pragma unroll
        for (int dt = 0; dt < 4; ++dt) {
            half8 vf0 = *(const half8*)&sVt[dt * 16 + l16][quad * 8];      // A[m=d][k=kpos]
            half8 vf1 = *(const half8*)&sVt[dt * 16 + l16][32 + quad * 8];
            acc[dt] = __builtin_amdgcn_mfma_f32_16x16x32_f16(vf0, pf0, acc[dt], 0, 0, 0);
            acc[dt] = __builtin_amdgcn_mfma_f32_16x16x32_f16(vf1, pf1, acc[dt], 0, 0, 0);
        }
    }

    // final: reduce row-sum across quads, normalize, store half4 chunks
    l_run += __shfl_xor(l_run, 16);
    l_run += __shfl_xor(l_run, 32);
    const float inv = 1.0f / l_run;
    const size_t qg = (size_t)(b * 1024 + q0 + wave * 16 + l16);
    #pragma unroll
    for (int dt = 0; dt < 4; ++dt) {
        half4_t o;
        #pragma unroll
        for (int r = 0; r < 4; ++r) o[r] = (_Float16)(acc[dt][r] * inv);
        *(half4_t*)&ctx[qg * 1024 + h * 64 + dt * 16 + quad * 4] = o;
    }
}

// ---------------- launch ----------------
extern "C" void kernel_launch(void* const* d_in, const int* in_sizes, int n_in,
                              void* d_out, int out_size, void* d_ws, size_t ws_size,
                              hipStream_t stream) {
    const float* hidden   = (const float*)d_in[0];
    const float* Wq       = (const float*)d_in[1];
    const float* Wk       = (const float*)d_in[2];
    const float* Wv       = (const float*)d_in[3];
    const float* Wo       = (const float*)d_in[4];
    const float* rel_bias = (const float*)d_in[5];
    float* out = (float*)d_out;

    _Float16* ws    = (_Float16*)d_ws;
    _Float16* h16   = ws;                     // 4M halves (reused as VT after gemm_qkv)
    _Float16* wq16  = ws + 4 * (size_t)MEG;
    _Float16* wk16  = ws + 5 * (size_t)MEG;
    _Float16* wv16  = ws + 6 * (size_t)MEG;
    _Float16* wo16  = ws + 7 * (size_t)MEG;
    _Float16* Qs    = ws + 8 * (size_t)MEG;   // [B,H,S,64]
    _Float16* Ks    = ws + 12 * (size_t)MEG;
    _Float16* Vs    = ws + 16 * (size_t)MEG;
    _Float16* ctx16 = ws + 20 * (size_t)MEG;  // [B*S,1024]
    _Float16* VTs   = h16;                    // V^T [B,H,64,S] — h16 dead after gemm_qkv

    cvt_all_kernel<<<8192, 256, 0, stream>>>(hidden, Wq, Wk, Wv, Wo, ws);

    gemm_qkv_kernel<<<dim3(8, 32, 3), 256, 0, stream>>>(
        h16, wq16, wk16, wv16, Qs, Ks, Vs);

    transpose_v_kernel<<<dim3(16, 64), 256, 0, stream>>>(Vs, VTs);

    attn_kernel<<<dim3(16, 16, 4), 256, 0, stream>>>(Qs, Ks, VTs, rel_bias, ctx16);

    gemm_o_kernel<<<dim3(8, 64), 256, 0, stream>>>(ctx16, wo16, out);
}